// Round 6
// baseline (307.477 us; speedup 1.0000x reference)
//
#include <hip/hip_runtime.h>

static constexpr int    kN = 200000;
static constexpr int    kC = 20;
static constexpr int    kP = 256;
static constexpr int    kM = 400000;
static constexpr int    kThreshPts = 100;
static constexpr int    kRowCap = 2048;                  // 12 sigma above mean 1562
static constexpr int    kLWords = kN / 32;               // 6250 LDS words per row
static constexpr int    kBlocks = 256;                   // 1 block/CU, co-resident
static constexpr int    kThreads = 1024;
static constexpr int    kChunk4 = (kM / 4 + kBlocks - 1) / kBlocks;  // 391 int4/block

typedef float nfloat4 __attribute__((ext_vector_type(4)));

// output layout (float elements)
static constexpr size_t OFF_SCORES  = 0;
static constexpr size_t OFF_MASKS   = 256;
static constexpr size_t OFF_CLASSES = OFF_MASKS + (size_t)kP * kN;   // 51200256
static constexpr size_t OFF_BIAS    = OFF_CLASSES + 256;             // 51200512
static constexpr size_t OFF_PROBS   = OFF_BIAS + 3 * (size_t)kN;     // 51800512

// workspace layout (bytes)
static constexpr size_t WS_CURSOR = 0;                               // int[256]
static constexpr size_t WS_BAR    = 1024;                            // int (grid barrier)
static constexpr size_t WS_SEG    = 1152;                            // int[kN]
static constexpr size_t WS_ROWBUF = WS_SEG + (size_t)kN * 4;         // int[256*2048]

// Single fused kernel. Phase A: softmax+argmax+probs+bias (one point per
// thread, 262144 threads >= 200000) and pair bucketing (391 int4 per block,
// LDS histogram -> one cursor atomic per nonzero bucket -> rowbuf scatter).
// Grid barrier (device-scope acq/rel; 256 blocks of 16 waves = 1 block/CU,
// all co-resident by capacity, so the spin cannot deadlock).
// Phase B: round-1 k_row body verbatim (LDS bitmap dedup w/ ownership,
// count/min reduce, class+flag, plain dwordx4 mask expansion, score).
__global__ void __launch_bounds__(1024)
k_fused(const float* __restrict__ logit,
        const float* __restrict__ bias,
        const int4* __restrict__ prop4,
        const int4* __restrict__ pt4,
        int* __restrict__ cursor,
        int* __restrict__ bar,
        int* __restrict__ rowbuf,
        int* __restrict__ seg,
        float* __restrict__ out) {
    __shared__ int s_cnt[kP];
    __shared__ int s_off[kP];
    __shared__ unsigned int lbits[kLWords];              // 25 KB
    __shared__ int   s_redc[16];
    __shared__ int   s_redm[16];
    __shared__ float s_redf[16];
    __shared__ int   s_cls;
    __shared__ float s_fv;

    const int t = threadIdx.x;
    const int b = blockIdx.x;
    const int gtid = b * kThreads + t;

    // ---------------- phase A1: softmax + bias ----------------
    if (gtid < 150000) {                                 // 600000 floats / 4
        const float4* b4 = (const float4*)bias;
        float4*       o4 = (float4*)(out + OFF_BIAS);
        o4[gtid] = b4[gtid];
    }
    if (gtid < kN) {
        const float4* l4 = (const float4*)(logit + (size_t)gtid * kC);
        float v[kC];
#pragma unroll
        for (int c = 0; c < 5; c++) {
            float4 x = l4[c];
            v[4*c] = x.x; v[4*c+1] = x.y; v[4*c+2] = x.z; v[4*c+3] = x.w;
        }
        float m = v[0]; int arg = 0;
#pragma unroll
        for (int i = 1; i < kC; i++) if (v[i] > m) { m = v[i]; arg = i; }
        float s = 0.0f;
#pragma unroll
        for (int i = 0; i < kC; i++) { v[i] = __expf(v[i] - m); s += v[i]; }
        float inv = 1.0f / s;
        float4* p4 = (float4*)(out + OFF_PROBS + (size_t)gtid * kC);
#pragma unroll
        for (int c = 0; c < 5; c++) {
            float4 x;
            x.x = v[4*c] * inv; x.y = v[4*c+1] * inv;
            x.z = v[4*c+2] * inv; x.w = v[4*c+3] * inv;
            p4[c] = x;
        }
        seg[gtid] = arg;
    }

    // ---------------- phase A2: bucket ----------------
    if (t < kP) s_cnt[t] = 0;
    __syncthreads();

    int idx = b * kChunk4 + t;                           // coalesced within block
    bool valid = (t < kChunk4) && (idx < kM / 4);
    int4 pv = {0, 0, 0, 0}, nv = {0, 0, 0, 0};
    int sl[4] = {0, 0, 0, 0};
    if (valid) {
        pv = prop4[idx];
        nv = pt4[idx];
        sl[0] = atomicAdd(&s_cnt[pv.x], 1);              // LDS atomics
        sl[1] = atomicAdd(&s_cnt[pv.y], 1);
        sl[2] = atomicAdd(&s_cnt[pv.z], 1);
        sl[3] = atomicAdd(&s_cnt[pv.w], 1);
    }
    __syncthreads();
    if (t < kP) s_off[t] = s_cnt[t] ? atomicAdd(&cursor[t], s_cnt[t]) : 0;
    __syncthreads();
    if (valid) {
        int d0 = s_off[pv.x] + sl[0];
        int d1 = s_off[pv.y] + sl[1];
        int d2 = s_off[pv.z] + sl[2];
        int d3 = s_off[pv.w] + sl[3];
        if (d0 < kRowCap) rowbuf[pv.x * kRowCap + d0] = nv.x;
        if (d1 < kRowCap) rowbuf[pv.y * kRowCap + d1] = nv.y;
        if (d2 < kRowCap) rowbuf[pv.z * kRowCap + d2] = nv.z;
        if (d3 < kRowCap) rowbuf[pv.w * kRowCap + d3] = nv.w;
    }

    // ---------------- grid barrier (release/acquire, agent scope) ----------
    __syncthreads();
    if (t == 0) {
        int arrived = __hip_atomic_fetch_add(bar, 1, __ATOMIC_ACQ_REL,
                                             __HIP_MEMORY_SCOPE_AGENT);
        if (arrived + 1 < kBlocks) {
            while (__hip_atomic_load(bar, __ATOMIC_ACQUIRE,
                                     __HIP_MEMORY_SCOPE_AGENT) < kBlocks) {
                __builtin_amdgcn_s_sleep(2);
            }
        }
    }
    __syncthreads();

    // ---------------- phase B: per-proposal row (round-1 body) ----------
    const int p = b;
    const float* probs = out + OFF_PROBS;

    for (int i = t; i < kLWords; i += kThreads) lbits[i] = 0;
    int len = cursor[p];
    if (len > kRowCap) len = kRowCap;
    __syncthreads();

    const int* rb = rowbuf + p * kRowCap;
    int  n0 = 0, n1 = 0;
    bool u0 = false, u1 = false;
    int  mymin = 0x7fffffff;
    if (t < len) {
        n0 = rb[t];
        unsigned int bit = 1u << (n0 & 31);
        unsigned int old = atomicOr(&lbits[(unsigned)n0 >> 5], bit);
        u0 = (old & bit) == 0u;                          // first setter owns n0
        mymin = n0;
    }
    if (t + kThreads < len) {
        n1 = rb[t + kThreads];
        unsigned int bit = 1u << (n1 & 31);
        unsigned int old = atomicOr(&lbits[(unsigned)n1 >> 5], bit);
        u1 = (old & bit) == 0u;
        mymin = n1 < mymin ? n1 : mymin;
    }

    int cnt = (int)u0 + (int)u1;
    for (int off = 32; off; off >>= 1) {
        cnt += __shfl_down(cnt, off);
        int om = __shfl_down(mymin, off);
        mymin = om < mymin ? om : mymin;
    }
    if ((t & 63) == 0) { s_redc[t >> 6] = cnt; s_redm[t >> 6] = mymin; }
    __syncthreads();
    int tot = 0;
    if (t == 0) {
        int mn = 0x7fffffff;
        for (int i = 0; i < 16; i++) {
            tot += s_redc[i];
            mn = s_redm[i] < mn ? s_redm[i] : mn;
        }
        int r = mn < 0 ? 0 : (mn > kN - 1 ? kN - 1 : mn);   // clip (empty -> N-1)
        int c = seg[r];
        bool fl = tot > kThreshPts;
        s_cls = c;
        s_fv  = fl ? 1.0f : 0.0f;
        out[OFF_CLASSES + p] = fl ? (float)c : -1.0f;
    }
    __syncthreads();

    float fv = s_fv;
    int   c  = s_cls;

    // score gathers: issue now, consume after the store stream
    float g0 = 0.0f, g1 = 0.0f;
    if (u0) g0 = probs[(size_t)n0 * kC + c];
    if (u1) g1 = probs[(size_t)n1 * kC + c];

    // expansion: plain cached dwordx4 store stream
    nfloat4* mrow = (nfloat4*)(out + OFF_MASKS) + (size_t)p * (kN / 4);
    for (int f = t; f < kN / 4; f += kThreads) {
        unsigned int word = lbits[f >> 3];
        unsigned int bb   = (word >> (((unsigned)f & 7u) * 4u)) & 0xFu;
        nfloat4 o;
        o.x = (bb & 1u) ? fv : 0.0f;
        o.y = (bb & 2u) ? fv : 0.0f;
        o.z = (bb & 4u) ? fv : 0.0f;
        o.w = (bb & 8u) ? fv : 0.0f;
        mrow[f] = o;
    }

    float s = g0 + g1;
    for (int off = 32; off; off >>= 1) s += __shfl_down(s, off);
    if ((t & 63) == 0) s_redf[t >> 6] = s;
    __syncthreads();
    if (t == 0) {
        float stot = 0.0f;
        for (int i = 0; i < 16; i++) stot += s_redf[i];
        float denom = (float)(tot > 1 ? tot : 1);
        out[OFF_SCORES + p] = (s_fv != 0.0f) ? stot / denom : 0.0f;
    }
}

extern "C" void kernel_launch(void* const* d_in, const int* in_sizes, int n_in,
                              void* d_out, int out_size, void* d_ws, size_t ws_size,
                              hipStream_t stream) {
    const float* logit = (const float*)d_in[0];
    const float* bias  = (const float*)d_in[1];
    // d_in[2] = coord: dead code in the reference (center_pred unused)
    const int4* prop4 = (const int4*)d_in[3];
    const int4* pt4   = (const int4*)d_in[4];
    float* out = (float*)d_out;
    char*  ws  = (char*)d_ws;

    int* cursor = (int*)(ws + WS_CURSOR);
    int* bar    = (int*)(ws + WS_BAR);
    int* seg    = (int*)(ws + WS_SEG);
    int* rowbuf = (int*)(ws + WS_ROWBUF);

    // zero cursor[256] + barrier counter (graph-capture-safe)
    hipMemsetAsync(ws, 0, WS_BAR + sizeof(int), stream);
    k_fused<<<kBlocks, kThreads, 0, stream>>>(
        logit, bias, prop4, pt4, cursor, bar, rowbuf, seg, out);
}

// Round 7
// 255.800 us; speedup vs baseline: 1.2020x; 1.2020x over previous
//
#include <hip/hip_runtime.h>

static constexpr int    kN = 200000;
static constexpr int    kC = 20;
static constexpr int    kP = 256;
static constexpr int    kM = 400000;
static constexpr int    kThreshPts = 100;
static constexpr int    kRowCap = 2048;                  // 12 sigma above mean 1562
static constexpr int    kLWords = kN / 32;               // 6250 LDS words per row

typedef float nfloat4 __attribute__((ext_vector_type(4)));

// output layout (float elements)
static constexpr size_t OFF_SCORES  = 0;
static constexpr size_t OFF_MASKS   = 256;
static constexpr size_t OFF_CLASSES = OFF_MASKS + (size_t)kP * kN;   // 51200256
static constexpr size_t OFF_BIAS    = OFF_CLASSES + 256;             // 51200512
static constexpr size_t OFF_PROBS   = OFF_BIAS + 3 * (size_t)kN;     // 51800512

// workspace layout (bytes)
static constexpr size_t WS_CURSOR = 0;                               // int[256]
static constexpr size_t WS_SEG    = 1024;                            // int[kN]
static constexpr size_t WS_ROWBUF = WS_SEG + (size_t)kN * 4;         // int[256*2048]

// K1: softmax + argmax per point; write probs; copy bias; zero cursor.
__global__ void k_softmax(const float* __restrict__ logit,
                          const float* __restrict__ bias,
                          float* __restrict__ out,
                          int* __restrict__ seg,
                          int* __restrict__ cursor) {
    int tid = blockIdx.x * blockDim.x + threadIdx.x;
    if (blockIdx.x == 0) cursor[threadIdx.x] = 0;        // block 0 is 256 threads

    // bias passthrough: 600000 floats = 150000 float4
    if (tid < 150000) {
        const float4* b4 = (const float4*)bias;
        float4*       o4 = (float4*)(out + OFF_BIAS);
        o4[tid] = b4[tid];
    }
    if (tid >= kN) return;

    const float4* l4 = (const float4*)(logit + (size_t)tid * kC);
    float v[kC];
#pragma unroll
    for (int c = 0; c < 5; c++) {
        float4 t = l4[c];
        v[4*c] = t.x; v[4*c+1] = t.y; v[4*c+2] = t.z; v[4*c+3] = t.w;
    }
    float m = v[0]; int arg = 0;
#pragma unroll
    for (int i = 1; i < kC; i++) if (v[i] > m) { m = v[i]; arg = i; }   // first max
    float s = 0.0f;
#pragma unroll
    for (int i = 0; i < kC; i++) { v[i] = __expf(v[i] - m); s += v[i]; }
    float inv = 1.0f / s;
    float4* p4 = (float4*)(out + OFF_PROBS + (size_t)tid * kC);
#pragma unroll
    for (int c = 0; c < 5; c++) {
        float4 t;
        t.x = v[4*c] * inv; t.y = v[4*c+1] * inv;
        t.z = v[4*c+2] * inv; t.w = v[4*c+3] * inv;
        p4[c] = t;
    }
    seg[tid] = arg;
}

// K2: bucket pairs by proposal. int4 pair loads, LDS histogram -> one global
// atomic per (block,row) -> plain stores.
__global__ void k_bucket(const int4* __restrict__ prop4,
                         const int4* __restrict__ pt4,
                         int* __restrict__ cursor,
                         int* __restrict__ rowbuf) {
    __shared__ int s_cnt[kP];
    __shared__ int s_off[kP];
    int t = threadIdx.x;                                 // 1024 threads
    if (t < kP) s_cnt[t] = 0;
    __syncthreads();

    int idx = blockIdx.x * 1024 + t;                     // one int4 = 4 pairs
    bool valid = idx < (kM / 4);
    int4 pv = {0, 0, 0, 0}, nv = {0, 0, 0, 0};
    int sl[4] = {0, 0, 0, 0};
    if (valid) {
        pv = prop4[idx];
        nv = pt4[idx];
        sl[0] = atomicAdd(&s_cnt[pv.x], 1);              // LDS atomics
        sl[1] = atomicAdd(&s_cnt[pv.y], 1);
        sl[2] = atomicAdd(&s_cnt[pv.z], 1);
        sl[3] = atomicAdd(&s_cnt[pv.w], 1);
    }
    __syncthreads();
    if (t < kP) s_off[t] = s_cnt[t] ? atomicAdd(&cursor[t], s_cnt[t]) : 0;
    __syncthreads();
    if (valid) {
        int d0 = s_off[pv.x] + sl[0];
        int d1 = s_off[pv.y] + sl[1];
        int d2 = s_off[pv.z] + sl[2];
        int d3 = s_off[pv.w] + sl[3];
        if (d0 < kRowCap) rowbuf[pv.x * kRowCap + d0] = nv.x;
        if (d1 < kRowCap) rowbuf[pv.y * kRowCap + d1] = nv.y;
        if (d2 < kRowCap) rowbuf[pv.z * kRowCap + d2] = nv.z;
        if (d3 < kRowCap) rowbuf[pv.w * kRowCap + d3] = nv.w;
    }
}

// K3: one block (1024 thr) per proposal. In-LDS bitmap: dedup via atomicOr
// ownership, count/min reduce, class+flag, plain dwordx4 mask expansion
// (probed at ~fill speed: NT/plain/device-wide/memset+scatter all within
// noise or worse), hoisted score gathers, score reduce.
// This is the round-1 source verbatim — best measured variant (255.8 us).
__global__ void __launch_bounds__(1024)
k_row(const int* __restrict__ rowbuf,
      const int* __restrict__ cursor,
      const int* __restrict__ seg,
      float* __restrict__ out) {
    __shared__ unsigned int lbits[kLWords];              // 25 KB
    __shared__ int   s_redc[16];
    __shared__ int   s_redm[16];
    __shared__ float s_redf[16];
    __shared__ int   s_cls;
    __shared__ float s_fv;

    int p = blockIdx.x;
    int t = threadIdx.x;
    const float* probs = out + OFF_PROBS;

    for (int i = t; i < kLWords; i += 1024) lbits[i] = 0;
    int len = cursor[p];
    if (len > kRowCap) len = kRowCap;
    __syncthreads();

    // pass 1: dedup with ownership
    const int* rb = rowbuf + p * kRowCap;
    int  n0 = 0, n1 = 0;
    bool u0 = false, u1 = false;
    int  mymin = 0x7fffffff;
    if (t < len) {
        n0 = rb[t];
        unsigned int bit = 1u << (n0 & 31);
        unsigned int old = atomicOr(&lbits[(unsigned)n0 >> 5], bit);
        u0 = (old & bit) == 0u;                          // first setter owns n0
        mymin = n0;
    }
    if (t + 1024 < len) {
        n1 = rb[t + 1024];
        unsigned int bit = 1u << (n1 & 31);
        unsigned int old = atomicOr(&lbits[(unsigned)n1 >> 5], bit);
        u1 = (old & bit) == 0u;
        mymin = n1 < mymin ? n1 : mymin;
    }

    int cnt = (int)u0 + (int)u1;
    for (int off = 32; off; off >>= 1) {
        cnt += __shfl_down(cnt, off);
        int om = __shfl_down(mymin, off);
        mymin = om < mymin ? om : mymin;
    }
    if ((t & 63) == 0) { s_redc[t >> 6] = cnt; s_redm[t >> 6] = mymin; }
    __syncthreads();
    int tot = 0;
    if (t == 0) {
        int mn = 0x7fffffff;
        for (int i = 0; i < 16; i++) {
            tot += s_redc[i];
            mn = s_redm[i] < mn ? s_redm[i] : mn;
        }
        int r = mn < 0 ? 0 : (mn > kN - 1 ? kN - 1 : mn);   // clip (empty -> N-1)
        int c = seg[r];
        bool fl = tot > kThreshPts;
        s_cls = c;
        s_fv  = fl ? 1.0f : 0.0f;
        out[OFF_CLASSES + p] = fl ? (float)c : -1.0f;
    }
    __syncthreads();

    float fv = s_fv;
    int   c  = s_cls;

    // pass 2 gathers: issue now, consume after the store stream
    float g0 = 0.0f, g1 = 0.0f;
    if (u0) g0 = probs[(size_t)n0 * kC + c];
    if (u1) g1 = probs[(size_t)n1 * kC + c];

    // expansion: plain cached dwordx4 store stream
    nfloat4* mrow = (nfloat4*)(out + OFF_MASKS) + (size_t)p * (kN / 4);
    for (int f = t; f < kN / 4; f += 1024) {
        unsigned int word = lbits[f >> 3];
        unsigned int b    = (word >> (((unsigned)f & 7u) * 4u)) & 0xFu;
        nfloat4 o;
        o.x = (b & 1u) ? fv : 0.0f;
        o.y = (b & 2u) ? fv : 0.0f;
        o.z = (b & 4u) ? fv : 0.0f;
        o.w = (b & 8u) ? fv : 0.0f;
        mrow[f] = o;
    }

    float s = g0 + g1;
    for (int off = 32; off; off >>= 1) s += __shfl_down(s, off);
    if ((t & 63) == 0) s_redf[t >> 6] = s;
    __syncthreads();
    if (t == 0) {
        float stot = 0.0f;
        for (int i = 0; i < 16; i++) stot += s_redf[i];
        float denom = (float)(tot > 1 ? tot : 1);
        out[OFF_SCORES + p] = (s_fv != 0.0f) ? stot / denom : 0.0f;
    }
}

extern "C" void kernel_launch(void* const* d_in, const int* in_sizes, int n_in,
                              void* d_out, int out_size, void* d_ws, size_t ws_size,
                              hipStream_t stream) {
    const float* logit = (const float*)d_in[0];
    const float* bias  = (const float*)d_in[1];
    // d_in[2] = coord: dead code in the reference (center_pred unused)
    const int4* prop4 = (const int4*)d_in[3];
    const int4* pt4   = (const int4*)d_in[4];
    float* out = (float*)d_out;
    char*  ws  = (char*)d_ws;

    int* cursor = (int*)(ws + WS_CURSOR);
    int* seg    = (int*)(ws + WS_SEG);
    int* rowbuf = (int*)(ws + WS_ROWBUF);

    k_softmax<<<(kN + 255) / 256, 256, 0, stream>>>(logit, bias, out, seg, cursor);
    k_bucket<<<(kM / 4 + 1023) / 1024, 1024, 0, stream>>>(prop4, pt4, cursor, rowbuf);
    k_row<<<kP, 1024, 0, stream>>>(rowbuf, cursor, seg, out);
}